// Round 1
// baseline (303.120 us; speedup 1.0000x reference)
//
#include <hip/hip_runtime.h>

typedef unsigned short u16;
typedef u16 u16x4 __attribute__((ext_vector_type(4)));
typedef u16 u16x8 __attribute__((ext_vector_type(8)));
typedef float f32x4 __attribute__((ext_vector_type(4)));
typedef __bf16 bf16x8 __attribute__((ext_vector_type(8)));

#define M_DIM 8192   // B*H = 4*2048
#define N_DIM 1024   // O
#define K_DIM 4096   // I*(D+1) = 1024*4

__device__ __forceinline__ u16 f2bf(float f) {
  unsigned u = __float_as_uint(f);
  u += 0x7FFFu + ((u >> 16) & 1u);   // round-to-nearest-even
  return (u16)(u >> 16);
}

// ---- kernel 1: x fp32 -> bf16 (8 elems / thread, 32B read, 16B write) ----
__global__ __launch_bounds__(256) void k_cvt(const float* __restrict__ x,
                                             u16* __restrict__ y) {
  long i = ((long)blockIdx.x * 256 + threadIdx.x) * 8;
  f32x4 a = *(const f32x4*)(x + i);
  f32x4 b = *(const f32x4*)(x + i + 4);
  u16x8 r;
  r[0] = f2bf(a[0]); r[1] = f2bf(a[1]); r[2] = f2bf(a[2]); r[3] = f2bf(a[3]);
  r[4] = f2bf(b[0]); r[5] = f2bf(b[1]); r[6] = f2bf(b[2]); r[7] = f2bf(b[3]);
  *(u16x8*)(y + i) = r;
}

// ---- kernel 2: W2[o][i*4+d] = ws[o][i] * w[o][d], bf16 [N][K] ----
__global__ __launch_bounds__(256) void k_w2(const float* __restrict__ w,
                                            const float* __restrict__ ws,
                                            u16* __restrict__ w2) {
  int idx = blockIdx.x * 256 + threadIdx.x;  // idx = o*1024 + i
  int o = idx >> 10;
  float s = ws[idx];
  f32x4 wv = *(const f32x4*)(w + o * 4);
  u16x4 r;
  r[0] = f2bf(s * wv[0]); r[1] = f2bf(s * wv[1]);
  r[2] = f2bf(s * wv[2]); r[3] = f2bf(s * wv[3]);
  *(u16x4*)(w2 + (size_t)idx * 4) = r;
}

// ---- kernel 3: m97-style bf16 GEMM, C[M][N] = A[M][K] @ Bt[N][K]^T ----
typedef __attribute__((address_space(1))) const void gvoid_t;
typedef __attribute__((address_space(3))) void lvoid_t;
__device__ __forceinline__ void gll16(const void* g, void* l) {
  __builtin_amdgcn_global_load_lds((gvoid_t*)g, (lvoid_t*)l, 16, 0, 0);
}

__global__ __launch_bounds__(256) void k_gemm(const u16* __restrict__ A,
                                              const u16* __restrict__ Bt,
                                              float* __restrict__ C) {
  __shared__ u16 sA[128 * 32];  // 8 KB, unpadded: global_load_lds lane-contiguous
  __shared__ u16 sB[128 * 32];  // 8 KB

  const int t    = threadIdx.x;
  const int lane = t & 63;
  const int wid  = t >> 6;
  const int m0   = blockIdx.y * 128;
  const int n0   = blockIdx.x * 128;

  // staging: chunk c = t (+256 for 2nd round); row = c>>2, k-off = (c&3)*8
  const int row0 = t >> 2;
  const int kc0  = (t & 3) * 8;
  const u16* gA0 = A  + (size_t)(m0 + row0) * K_DIM + kc0;
  const u16* gA1 = gA0 + (size_t)64 * K_DIM;
  const u16* gB0 = Bt + (size_t)(n0 + row0) * K_DIM + kc0;
  const u16* gB1 = gB0 + (size_t)64 * K_DIM;
  u16* lA0 = sA + t * 8;
  u16* lA1 = sA + (t + 256) * 8;
  u16* lB0 = sB + t * 8;
  u16* lB1 = sB + (t + 256) * 8;

  // wave tile: 2x2 waves of 64x64, each 4x4 MFMA 16x16
  const int wm = (wid >> 1) * 64;
  const int wn = (wid & 1) * 64;
  const int fr = lane & 15;         // A/B fragment row: m (or n) = lane&15
  const int kg = (lane >> 4) * 8;   // k = (lane>>4)*8 + j

  f32x4 acc[4][4];
#pragma unroll
  for (int i = 0; i < 4; i++)
#pragma unroll
    for (int j = 0; j < 4; j++) acc[i][j] = (f32x4){0.f, 0.f, 0.f, 0.f};

  for (int k0 = 0; k0 < K_DIM; k0 += 32) {
    gll16(gA0, lA0); gll16(gA1, lA1);
    gll16(gB0, lB0); gll16(gB1, lB1);
    gA0 += 32; gA1 += 32; gB0 += 32; gB1 += 32;
    __syncthreads();  // barrier drains vmcnt -> LDS tiles ready

    bf16x8 af[4], bf[4];
#pragma unroll
    for (int mi = 0; mi < 4; mi++)
      af[mi] = *(const bf16x8*)(sA + (wm + mi * 16 + fr) * 32 + kg);
#pragma unroll
    for (int ni = 0; ni < 4; ni++)
      bf[ni] = *(const bf16x8*)(sB + (wn + ni * 16 + fr) * 32 + kg);

#pragma unroll
    for (int mi = 0; mi < 4; mi++)
#pragma unroll
      for (int ni = 0; ni < 4; ni++)
        acc[mi][ni] = __builtin_amdgcn_mfma_f32_16x16x32_bf16(
            af[mi], bf[ni], acc[mi][ni], 0, 0, 0);
    __syncthreads();  // protect LDS from next iteration's staging
  }

  // C/D layout: col = lane&15, row = (lane>>4)*4 + reg
  const int cr = (lane >> 4) * 4;
  const int cc = lane & 15;
#pragma unroll
  for (int mi = 0; mi < 4; mi++)
#pragma unroll
    for (int ni = 0; ni < 4; ni++) {
      float* cp = C + (size_t)(m0 + wm + mi * 16 + cr) * N_DIM +
                  (n0 + wn + ni * 16 + cc);
#pragma unroll
      for (int r = 0; r < 4; r++) cp[(size_t)r * N_DIM] = acc[mi][ni][r];
    }
}

extern "C" void kernel_launch(void* const* d_in, const int* in_sizes, int n_in,
                              void* d_out, int out_size, void* d_ws, size_t ws_size,
                              hipStream_t stream) {
  const float* x  = (const float*)d_in[0];   // (4,2048,1024,4) fp32
  const float* w  = (const float*)d_in[1];   // (1024,4) fp32
  const float* ws = (const float*)d_in[2];   // (1024,1024) fp32
  float* out = (float*)d_out;                // (4,2048,1024) fp32 = C[M][N]

  u16* xbf = (u16*)d_ws;                         // 33.5M u16 = 64 MB
  u16* w2  = xbf + (size_t)M_DIM * K_DIM;        // 4.2M u16 = 8 MB

  // 33,554,432 / (256*8) = 16384 blocks
  k_cvt<<<16384, 256, 0, stream>>>(x, xbf);
  // 1,048,576 / 256 = 4096 blocks
  k_w2<<<4096, 256, 0, stream>>>(w, ws, w2);

  dim3 grid(N_DIM / 128, M_DIM / 128);  // (8, 64) = 512 blocks
  k_gemm<<<grid, 256, 0, stream>>>(xbf, w2, out);
}